// Round 7
// baseline (359.415 us; speedup 1.0000x reference)
//
#include <hip/hip_runtime.h>
#include <math.h>

#define IN_CH 256
#define OUT_CH 64
#define SCHUNK 512  // scan elements per block (needs n <= 256*SCHUNK = 131072)

// ---------- monotonic float<->uint mapping for atomic max ----------
__device__ __forceinline__ unsigned fmap(float f) {
  unsigned u = __float_as_uint(f);
  return (u & 0x80000000u) ? ~u : (u | 0x80000000u);
}
__device__ __forceinline__ float funmap(unsigned u) {
  return (u & 0x80000000u) ? __uint_as_float(u & 0x7fffffffu) : __uint_as_float(~u);
}

// ---------- K1: Wh = x @ W ; e = Wh . (a_src + a_dst) ; gmax = max(e) ----------
// Weights-in-VGPR GEMV: 1 wave = 1 row, lane = output channel.
// W[k][lane] lives in 256 VGPRs (fully unrolled, static indices). x-row fetched via
// wave-uniform (readfirstlane'd) address -> scalar s_load; FMA uses SGPR broadcast.
// No LDS, no barriers.
__global__ __launch_bounds__(256, 1) void gat_gemv(
    const float* __restrict__ x, const float* __restrict__ W,
    const float* __restrict__ a_src, const float* __restrict__ a_dst,
    float* __restrict__ Wh, float* __restrict__ e, unsigned* __restrict__ gmax,
    int n, int rows_per_wave)
{
  const int lane = threadIdx.x & 63;
  const int gwave = blockIdx.x * (blockDim.x >> 6) + (threadIdx.x >> 6);

  float w[IN_CH];
#pragma unroll
  for (int k = 0; k < IN_CH; ++k) w[k] = W[(size_t)k * OUT_CH + lane];  // coalesced, L2-hot
  const float asd = a_src[lane] + a_dst[lane];

  const int row0 = gwave * rows_per_wave;
  if (row0 >= n) return;
  int rend = row0 + rows_per_wave; if (rend > n) rend = n;

  float vmax = -INFINITY;
  for (int rr = row0; rr < rend; ++rr) {
    const int row = __builtin_amdgcn_readfirstlane(rr);   // force SGPR -> s_load path
    const float* __restrict__ xr = x + (size_t)row * IN_CH;
    float a0 = 0.f, a1 = 0.f, a2 = 0.f, a3 = 0.f;
#pragma unroll
    for (int k = 0; k < IN_CH; k += 4) {
      a0 = fmaf(xr[k + 0], w[k + 0], a0);
      a1 = fmaf(xr[k + 1], w[k + 1], a1);
      a2 = fmaf(xr[k + 2], w[k + 2], a2);
      a3 = fmaf(xr[k + 3], w[k + 3], a3);
    }
    float acc = (a0 + a1) + (a2 + a3);
    Wh[(size_t)row * OUT_CH + lane] = acc;
    float v = acc * asd;                      // e[row] = sum over channels
#pragma unroll
    for (int m = 1; m < 64; m <<= 1) v += __shfl_xor(v, m);
    if (lane == 0) e[row] = v;
    vmax = fmaxf(vmax, v);                    // v is full sum in every lane
  }
  if (lane == 0) atomicMax(gmax, fmap(vmax));
}

// ---------- K2: detect int64 vs int32 edge_index ----------
__global__ void gat_detect64(const unsigned* __restrict__ eidx, unsigned* __restrict__ flag, int npairs)
{
  unsigned v = 0;
  for (int i = threadIdx.x; i < npairs; i += blockDim.x) v |= eidx[2 * i + 1];
#pragma unroll
  for (int m = 32; m >= 1; m >>= 1) v |= __shfl_xor(v, m);
  if ((threadIdx.x & 63) == 0) atomicOr(flag, v);
}

// ---------- K3: count degrees (reads only the col half of eidx) ----------
__global__ void gat_pass1(
    const void* __restrict__ eidx, const unsigned* __restrict__ flag,
    int* __restrict__ cnt, int E)
{
  int j = blockIdx.x * blockDim.x + threadIdx.x;
  if (j >= E) return;
  int c;
  if (*flag == 0) {  // int64: low word of element E+j
    const unsigned* p = (const unsigned*)eidx;
    c = (int)p[2 * ((size_t)E + j)];
  } else {
    const int* p = (const int*)eidx;
    c = p[(size_t)E + j];
  }
  atomicAdd(cnt + c, 1);
}

// ---------- K4a/b/c: hierarchical exclusive scan of cnt -> segp, cursor ----------
__global__ __launch_bounds__(256) void scan_partial(
    const int* __restrict__ cnt, int* __restrict__ bsum, int n)
{
  int base = blockIdx.x * SCHUNK;
  int tid = threadIdx.x;
  int s = 0;
  int i0 = base + tid, i1 = base + tid + 256;
  if (i0 < n) s += cnt[i0];
  if (i1 < n) s += cnt[i1];
#pragma unroll
  for (int m = 1; m < 64; m <<= 1) s += __shfl_xor(s, m);
  __shared__ int ws[4];
  if ((tid & 63) == 0) ws[tid >> 6] = s;
  __syncthreads();
  if (tid == 0) bsum[blockIdx.x] = ws[0] + ws[1] + ws[2] + ws[3];
}

__global__ __launch_bounds__(256) void scan_bsum(
    int* __restrict__ bsum, int* __restrict__ segp, int nb, int n, int E)
{
  __shared__ int sh[256];
  int tid = threadIdx.x;
  int v = (tid < nb) ? bsum[tid] : 0;
  sh[tid] = v;
  __syncthreads();
  for (int off = 1; off < 256; off <<= 1) {
    int add = (tid >= off) ? sh[tid - off] : 0;
    __syncthreads();
    sh[tid] += add;
    __syncthreads();
  }
  if (tid < nb) bsum[tid] = sh[tid] - v;   // exclusive block offsets
  if (tid == 0) segp[n] = E;
}

__global__ __launch_bounds__(256) void scan_final(
    const int* __restrict__ cnt, const int* __restrict__ bsum,
    int* __restrict__ segp, int* __restrict__ cursor, int n)
{
  int base = blockIdx.x * SCHUNK;
  int tid = threadIdx.x;
  int i0 = base + 2 * tid, i1 = i0 + 1;
  int c0 = (i0 < n) ? cnt[i0] : 0;
  int c1 = (i1 < n) ? cnt[i1] : 0;
  int ps = c0 + c1;
  __shared__ int sh[256];
  sh[tid] = ps;
  __syncthreads();
  for (int off = 1; off < 256; off <<= 1) {
    int add = (tid >= off) ? sh[tid - off] : 0;
    __syncthreads();
    sh[tid] += add;
    __syncthreads();
  }
  int excl = sh[tid] - ps + bsum[blockIdx.x];
  if (i0 < n) { segp[i0] = excl;      cursor[i0] = excl; }
  if (i1 < n) { segp[i1] = excl + c0; cursor[i1] = excl + c0; }
}

// ---------- K5: pure CSR scatter — IDX bytes per edge (row id only) ----------
template <typename IDX>
__global__ void gat_scatter(
    const void* __restrict__ eidx, const unsigned* __restrict__ flag,
    int* __restrict__ cursor, IDX* __restrict__ perm, int E)
{
  int j = blockIdx.x * blockDim.x + threadIdx.x;
  if (j >= E) return;
  int r, c;
  if (*flag == 0) {
    const long long* p = (const long long*)eidx;
    r = (int)p[j]; c = (int)p[(size_t)E + j];
  } else {
    const int* p = (const int*)eidx;
    r = p[j]; c = p[(size_t)E + j];
  }
  int pos = atomicAdd(cursor + c, 1);
  perm[pos] = (IDX)r;
}

// ---------- K6: aggregate + ELU; recompute ev in-loop (1 wave/node, lane=channel) ----------
template <typename IDX>
__global__ __launch_bounds__(256) void gat_aggregate(
    const float* __restrict__ Wh, const float* __restrict__ e,
    const unsigned* __restrict__ gmax, const IDX* __restrict__ perm,
    const int* __restrict__ segp, float* __restrict__ out, int n)
{
  int wave = threadIdx.x >> 6, lane = threadIdx.x & 63;
  int c = blockIdx.x * 4 + wave;
  if (c >= n) return;
  int p0 = segp[c], p1 = segp[c + 1];
  float s = 2.0f * funmap(*gmax);
  float ec = e[c] - s;

  float a0 = 0.f, a1 = 0.f, a2 = 0.f, a3 = 0.f;
  float s0 = 0.f, s1 = 0.f, s2 = 0.f, s3 = 0.f;
  int p = p0;
  for (; p + 4 <= p1; p += 4) {
    unsigned r0 = (unsigned)perm[p],     r1 = (unsigned)perm[p + 1];
    unsigned r2 = (unsigned)perm[p + 2], r3 = (unsigned)perm[p + 3];
    float e0 = e[r0], e1 = e[r1], e2 = e[r2], e3 = e[r3];
    float w0 = Wh[(size_t)r0 * OUT_CH + lane];
    float w1 = Wh[(size_t)r1 * OUT_CH + lane];
    float w2 = Wh[(size_t)r2 * OUT_CH + lane];
    float w3 = Wh[(size_t)r3 * OUT_CH + lane];
    float v0 = __expf(e0 + ec), v1 = __expf(e1 + ec);
    float v2 = __expf(e2 + ec), v3 = __expf(e3 + ec);
    a0 = fmaf(v0, w0, a0); s0 += v0;
    a1 = fmaf(v1, w1, a1); s1 += v1;
    a2 = fmaf(v2, w2, a2); s2 += v2;
    a3 = fmaf(v3, w3, a3); s3 += v3;
  }
  for (; p < p1; ++p) {
    unsigned r = (unsigned)perm[p];
    float v = __expf(e[r] + ec);
    a0 = fmaf(v, Wh[(size_t)r * OUT_CH + lane], a0); s0 += v;
  }
  float acc = (a0 + a1) + (a2 + a3);
  float ssum = (s0 + s1) + (s2 + s3);
  float rden = (p1 > p0) ? 1.0f / ssum : 0.0f;  // empty segment -> elu(0)=0
  acc *= rden;
  out[(size_t)c * OUT_CH + lane] = acc > 0.f ? acc : expm1f(acc);
}

extern "C" void kernel_launch(void* const* d_in, const int* in_sizes, int n_in,
                              void* d_out, int out_size, void* d_ws, size_t ws_size,
                              hipStream_t stream)
{
  const float* x     = (const float*)d_in[0];
  const void*  eidx  = d_in[1];
  const float* W     = (const float*)d_in[2];
  const float* a_src = (const float*)d_in[3];
  const float* a_dst = (const float*)d_in[4];
  float* out = (float*)d_out;

  const int n = in_sizes[0] / IN_CH;   // 50000
  const int E = in_sizes[1] / 2;       // 800000
  const int nb = (n + SCHUNK - 1) / SCHUNK;

  char* ws = (char*)d_ws;
  size_t off = 0;
  auto alloc = [&](size_t bytes) -> void* {
    void* p = ws + off;
    off = (off + bytes + 255) & ~(size_t)255;
    return p;
  };
  float*    Wh     = (float*)alloc((size_t)n * OUT_CH * 4);
  float*    e      = (float*)alloc((size_t)n * 4);
  void*     perm   = alloc((size_t)E * 4);   // ushort or uint, by n
  int*      cnt    = (int*)alloc((size_t)n * 4);
  int*      segp   = (int*)alloc((size_t)(n + 1) * 4);
  int*      cursor = (int*)alloc((size_t)n * 4);
  int*      bsum   = (int*)alloc((size_t)nb * 4);
  unsigned* gmax   = (unsigned*)alloc(4);
  unsigned* flag   = (unsigned*)alloc(4);

  hipMemsetAsync(cnt,  0, (size_t)n * 4, stream);
  hipMemsetAsync(gmax, 0, 4, stream);
  hipMemsetAsync(flag, 0, 4, stream);

  // 512 blocks x 4 waves = 2048 waves; each wave owns ceil(n/2048) rows.
  const int gemv_blocks = 512;
  const int total_waves = gemv_blocks * 4;
  const int rpw = (n + total_waves - 1) / total_waves;
  gat_gemv<<<gemv_blocks, 256, 0, stream>>>(x, W, a_src, a_dst, Wh, e, gmax, n, rpw);

  gat_detect64<<<1, 256, 0, stream>>>((const unsigned*)eidx, flag, 8192);
  gat_pass1<<<(E + 255) / 256, 256, 0, stream>>>(eidx, flag, cnt, E);
  scan_partial<<<nb, 256, 0, stream>>>(cnt, bsum, n);
  scan_bsum<<<1, 256, 0, stream>>>(bsum, segp, nb, n, E);
  scan_final<<<nb, 256, 0, stream>>>(cnt, bsum, segp, cursor, n);
  if (n <= 65536) {
    gat_scatter<unsigned short><<<(E + 255) / 256, 256, 0, stream>>>(
        eidx, flag, cursor, (unsigned short*)perm, E);
    gat_aggregate<unsigned short><<<(n + 3) / 4, 256, 0, stream>>>(
        Wh, e, gmax, (const unsigned short*)perm, segp, out, n);
  } else {
    gat_scatter<unsigned><<<(E + 255) / 256, 256, 0, stream>>>(
        eidx, flag, cursor, (unsigned*)perm, E);
    gat_aggregate<unsigned><<<(n + 3) / 4, 256, 0, stream>>>(
        Wh, e, gmax, (const unsigned*)perm, segp, out, n);
  }
}

// Round 9
// 221.304 us; speedup vs baseline: 1.6241x; 1.6241x over previous
//
#include <hip/hip_runtime.h>
#include <math.h>

#define IN_CH 256
#define OUT_CH 64
#define SCHUNK 512  // scan elements per block (needs n <= 256*SCHUNK = 131072)

typedef unsigned short ushort;
typedef unsigned short ushort8 __attribute__((ext_vector_type(8)));
typedef __bf16 bf16x8 __attribute__((ext_vector_type(8)));
typedef float f32x4 __attribute__((ext_vector_type(4)));

// ---------- monotonic float<->uint mapping for atomic max ----------
__device__ __forceinline__ unsigned fmap(float f) {
  unsigned u = __float_as_uint(f);
  return (u & 0x80000000u) ? ~u : (u | 0x80000000u);
}
__device__ __forceinline__ float funmap(unsigned u) {
  return (u & 0x80000000u) ? __uint_as_float(u & 0x7fffffffu) : __uint_as_float(~u);
}

__device__ __forceinline__ ushort bf16rne(float v) {
  unsigned u = __float_as_uint(v);
  return (ushort)((u + 0x7FFFu + ((u >> 16) & 1u)) >> 16);
}

// ---------- K0: split W into bf16 hi/lo, transposed to [col][k] (k-contiguous) ----------
__global__ __launch_bounds__(256) void gat_wprep(
    const float* __restrict__ W, ushort* __restrict__ Whi, ushort* __restrict__ Wlo)
{
  int i = blockIdx.x * 256 + threadIdx.x;          // 16384 = 256k x 64col
  if (i >= IN_CH * OUT_CH) return;
  int k = i >> 6, col = i & 63;
  float v = W[i];
  unsigned u = __float_as_uint(v);
  unsigned hb = (u + 0x7FFFu + ((u >> 16) & 1u)) & 0xFFFF0000u;  // RNE bf16, kept as fp32 bits
  float hf = __uint_as_float(hb);
  Whi[col * IN_CH + k] = (ushort)(hb >> 16);
  Wlo[col * IN_CH + k] = bf16rne(v - hf);
}

// ---------- K1: Wh = x @ W via split-bf16 MFMA ; e = Wh.(a_src+a_dst) ; gmax ----------
// 4 waves/block, wave = one 16-row group, no LDS, no barriers.
// A-frag: row = l&15, k = ks*32 + (l>>4)*8 + e   (fp32 loaded, converted in-register)
// B-frag: col = l&15, same k packing            (from prepped Whi/Wlo, L2-resident)
// D:      col = l&15, row = (l>>4)*4 + reg      (guide-verified m89/m91)
__global__ __launch_bounds__(256) void gat_gemm_mfma(
    const float* __restrict__ x, const ushort* __restrict__ Whi, const ushort* __restrict__ Wlo,
    const float* __restrict__ a_src, const float* __restrict__ a_dst,
    float* __restrict__ Wh, float* __restrict__ e, unsigned* __restrict__ gmax, int n)
{
  const int lane = threadIdx.x & 63;
  const int wave = threadIdx.x >> 6;
  const int row0 = blockIdx.x * 64 + wave * 16;
  const int lg = lane >> 4;              // 0..3 k-pack group
  const int li = lane & 15;              // row (A) / col (B/D) index
  const int kp = lg * 8;

  int arow = row0 + li; if (arow > n - 1) arow = n - 1;   // clamp; stores are guarded

  f32x4 acc[4] = {{0.f,0.f,0.f,0.f},{0.f,0.f,0.f,0.f},{0.f,0.f,0.f,0.f},{0.f,0.f,0.f,0.f}};
  float asd[4];
#pragma unroll
  for (int ct = 0; ct < 4; ++ct) {
    int col = ct * 16 + li;
    asd[ct] = a_src[col] + a_dst[col];
  }

  const float* __restrict__ xr = x + (size_t)arow * IN_CH + kp;
#pragma unroll 4
  for (int ks = 0; ks < 8; ++ks) {
    float4 v0 = *(const float4*)(xr + ks * 32);
    float4 v1 = *(const float4*)(xr + ks * 32 + 4);
    float vv[8] = {v0.x, v0.y, v0.z, v0.w, v1.x, v1.y, v1.z, v1.w};
    ushort8 ah_u, al_u;
#pragma unroll
    for (int t = 0; t < 8; ++t) {
      unsigned u = __float_as_uint(vv[t]);
      unsigned hb = (u + 0x7FFFu + ((u >> 16) & 1u)) & 0xFFFF0000u;
      ah_u[t] = (ushort)(hb >> 16);
      al_u[t] = bf16rne(vv[t] - __uint_as_float(hb));
    }
    bf16x8 ah = __builtin_bit_cast(bf16x8, ah_u);
    bf16x8 al = __builtin_bit_cast(bf16x8, al_u);
#pragma unroll
    for (int ct = 0; ct < 4; ++ct) {
      const size_t bo = (size_t)(ct * 16 + li) * IN_CH + ks * 32 + kp;
      bf16x8 bh = __builtin_bit_cast(bf16x8, *(const ushort8*)(Whi + bo));
      bf16x8 bl = __builtin_bit_cast(bf16x8, *(const ushort8*)(Wlo + bo));
      acc[ct] = __builtin_amdgcn_mfma_f32_16x16x32_bf16(ah, bh, acc[ct], 0, 0, 0);
      acc[ct] = __builtin_amdgcn_mfma_f32_16x16x32_bf16(ah, bl, acc[ct], 0, 0, 0);
      acc[ct] = __builtin_amdgcn_mfma_f32_16x16x32_bf16(al, bh, acc[ct], 0, 0, 0);
    }
  }

  // store Wh (D layout: row = lg*4 + r, col = ct*16 + li)
#pragma unroll
  for (int ct = 0; ct < 4; ++ct) {
    int col = ct * 16 + li;
#pragma unroll
    for (int r = 0; r < 4; ++r) {
      int row = row0 + lg * 4 + r;
      if (row < n) Wh[(size_t)row * OUT_CH + col] = acc[ct][r];
    }
  }

  // e[row] = sum_col D[row][col]*asd[col] ; gmax = max(e)
  float vmax = -INFINITY;
#pragma unroll
  for (int r = 0; r < 4; ++r) {
    float pe = acc[0][r] * asd[0] + acc[1][r] * asd[1] + acc[2][r] * asd[2] + acc[3][r] * asd[3];
    pe += __shfl_xor(pe, 1); pe += __shfl_xor(pe, 2); pe += __shfl_xor(pe, 4); pe += __shfl_xor(pe, 8);
    int row = row0 + lg * 4 + r;
    if (row < n) {
      if (li == 0) e[row] = pe;
      vmax = fmaxf(vmax, pe);
    }
  }
  vmax = fmaxf(vmax, __shfl_xor(vmax, 16));
  vmax = fmaxf(vmax, __shfl_xor(vmax, 32));
  if (lane == 0) atomicMax(gmax, fmap(vmax));
}

// ---------- K2: detect int64 vs int32 edge_index ----------
__global__ void gat_detect64(const unsigned* __restrict__ eidx, unsigned* __restrict__ flag, int npairs)
{
  unsigned v = 0;
  for (int i = threadIdx.x; i < npairs; i += blockDim.x) v |= eidx[2 * i + 1];
#pragma unroll
  for (int m = 32; m >= 1; m >>= 1) v |= __shfl_xor(v, m);
  if ((threadIdx.x & 63) == 0) atomicOr(flag, v);
}

// ---------- K3: count degrees (reads only the col half of eidx) ----------
__global__ void gat_pass1(
    const void* __restrict__ eidx, const unsigned* __restrict__ flag,
    int* __restrict__ cnt, int E)
{
  int j = blockIdx.x * blockDim.x + threadIdx.x;
  if (j >= E) return;
  int c;
  if (*flag == 0) {  // int64: low word of element E+j
    const unsigned* p = (const unsigned*)eidx;
    c = (int)p[2 * ((size_t)E + j)];
  } else {
    const int* p = (const int*)eidx;
    c = p[(size_t)E + j];
  }
  atomicAdd(cnt + c, 1);
}

// ---------- K4a/b/c: hierarchical exclusive scan of cnt -> segp, cursor ----------
__global__ __launch_bounds__(256) void scan_partial(
    const int* __restrict__ cnt, int* __restrict__ bsum, int n)
{
  int base = blockIdx.x * SCHUNK;
  int tid = threadIdx.x;
  int s = 0;
  int i0 = base + tid, i1 = base + tid + 256;
  if (i0 < n) s += cnt[i0];
  if (i1 < n) s += cnt[i1];
#pragma unroll
  for (int m = 1; m < 64; m <<= 1) s += __shfl_xor(s, m);
  __shared__ int ws[4];
  if ((tid & 63) == 0) ws[tid >> 6] = s;
  __syncthreads();
  if (tid == 0) bsum[blockIdx.x] = ws[0] + ws[1] + ws[2] + ws[3];
}

__global__ __launch_bounds__(256) void scan_bsum(
    int* __restrict__ bsum, int* __restrict__ segp, int nb, int n, int E)
{
  __shared__ int sh[256];
  int tid = threadIdx.x;
  int v = (tid < nb) ? bsum[tid] : 0;
  sh[tid] = v;
  __syncthreads();
  for (int off = 1; off < 256; off <<= 1) {
    int add = (tid >= off) ? sh[tid - off] : 0;
    __syncthreads();
    sh[tid] += add;
    __syncthreads();
  }
  if (tid < nb) bsum[tid] = sh[tid] - v;   // exclusive block offsets
  if (tid == 0) segp[n] = E;
}

__global__ __launch_bounds__(256) void scan_final(
    const int* __restrict__ cnt, const int* __restrict__ bsum,
    int* __restrict__ segp, int* __restrict__ cursor, int n)
{
  int base = blockIdx.x * SCHUNK;
  int tid = threadIdx.x;
  int i0 = base + 2 * tid, i1 = i0 + 1;
  int c0 = (i0 < n) ? cnt[i0] : 0;
  int c1 = (i1 < n) ? cnt[i1] : 0;
  int ps = c0 + c1;
  __shared__ int sh[256];
  sh[tid] = ps;
  __syncthreads();
  for (int off = 1; off < 256; off <<= 1) {
    int add = (tid >= off) ? sh[tid - off] : 0;
    __syncthreads();
    sh[tid] += add;
    __syncthreads();
  }
  int excl = sh[tid] - ps + bsum[blockIdx.x];
  if (i0 < n) { segp[i0] = excl;      cursor[i0] = excl; }
  if (i1 < n) { segp[i1] = excl + c0; cursor[i1] = excl + c0; }
}

// ---------- K5: pure CSR scatter — IDX bytes per edge (row id only) ----------
template <typename IDX>
__global__ void gat_scatter(
    const void* __restrict__ eidx, const unsigned* __restrict__ flag,
    int* __restrict__ cursor, IDX* __restrict__ perm, int E)
{
  int j = blockIdx.x * blockDim.x + threadIdx.x;
  if (j >= E) return;
  int r, c;
  if (*flag == 0) {
    const long long* p = (const long long*)eidx;
    r = (int)p[j]; c = (int)p[(size_t)E + j];
  } else {
    const int* p = (const int*)eidx;
    r = p[j]; c = p[(size_t)E + j];
  }
  int pos = atomicAdd(cursor + c, 1);
  perm[pos] = (IDX)r;
}

// ---------- K6: aggregate + ELU; recompute ev in-loop (1 wave/node, lane=channel) ----------
template <typename IDX>
__global__ __launch_bounds__(256) void gat_aggregate(
    const float* __restrict__ Wh, const float* __restrict__ e,
    const unsigned* __restrict__ gmax, const IDX* __restrict__ perm,
    const int* __restrict__ segp, float* __restrict__ out, int n)
{
  int wave = threadIdx.x >> 6, lane = threadIdx.x & 63;
  int c = blockIdx.x * 4 + wave;
  if (c >= n) return;
  int p0 = segp[c], p1 = segp[c + 1];
  float s = 2.0f * funmap(*gmax);
  float ec = e[c] - s;

  float a0 = 0.f, a1 = 0.f, a2 = 0.f, a3 = 0.f;
  float s0 = 0.f, s1 = 0.f, s2 = 0.f, s3 = 0.f;
  int p = p0;
  for (; p + 4 <= p1; p += 4) {
    unsigned r0 = (unsigned)perm[p],     r1 = (unsigned)perm[p + 1];
    unsigned r2 = (unsigned)perm[p + 2], r3 = (unsigned)perm[p + 3];
    float e0 = e[r0], e1 = e[r1], e2 = e[r2], e3 = e[r3];
    float w0 = Wh[(size_t)r0 * OUT_CH + lane];
    float w1 = Wh[(size_t)r1 * OUT_CH + lane];
    float w2 = Wh[(size_t)r2 * OUT_CH + lane];
    float w3 = Wh[(size_t)r3 * OUT_CH + lane];
    float v0 = __expf(e0 + ec), v1 = __expf(e1 + ec);
    float v2 = __expf(e2 + ec), v3 = __expf(e3 + ec);
    a0 = fmaf(v0, w0, a0); s0 += v0;
    a1 = fmaf(v1, w1, a1); s1 += v1;
    a2 = fmaf(v2, w2, a2); s2 += v2;
    a3 = fmaf(v3, w3, a3); s3 += v3;
  }
  for (; p < p1; ++p) {
    unsigned r = (unsigned)perm[p];
    float v = __expf(e[r] + ec);
    a0 = fmaf(v, Wh[(size_t)r * OUT_CH + lane], a0); s0 += v;
  }
  float acc = (a0 + a1) + (a2 + a3);
  float ssum = (s0 + s1) + (s2 + s3);
  float rden = (p1 > p0) ? 1.0f / ssum : 0.0f;  // empty segment -> elu(0)=0
  acc *= rden;
  out[(size_t)c * OUT_CH + lane] = acc > 0.f ? acc : expm1f(acc);
}

extern "C" void kernel_launch(void* const* d_in, const int* in_sizes, int n_in,
                              void* d_out, int out_size, void* d_ws, size_t ws_size,
                              hipStream_t stream)
{
  const float* x     = (const float*)d_in[0];
  const void*  eidx  = d_in[1];
  const float* W     = (const float*)d_in[2];
  const float* a_src = (const float*)d_in[3];
  const float* a_dst = (const float*)d_in[4];
  float* out = (float*)d_out;

  const int n = in_sizes[0] / IN_CH;   // 50000
  const int E = in_sizes[1] / 2;       // 800000
  const int nb = (n + SCHUNK - 1) / SCHUNK;

  char* ws = (char*)d_ws;
  size_t off = 0;
  auto alloc = [&](size_t bytes) -> void* {
    void* p = ws + off;
    off = (off + bytes + 255) & ~(size_t)255;
    return p;
  };
  float*    Wh     = (float*)alloc((size_t)n * OUT_CH * 4);
  float*    e      = (float*)alloc((size_t)n * 4);
  void*     perm   = alloc((size_t)E * 4);   // ushort or uint, by n
  int*      cnt    = (int*)alloc((size_t)n * 4);
  int*      segp   = (int*)alloc((size_t)(n + 1) * 4);
  int*      cursor = (int*)alloc((size_t)n * 4);
  int*      bsum   = (int*)alloc((size_t)nb * 4);
  ushort*   Whi    = (ushort*)alloc((size_t)IN_CH * OUT_CH * 2);
  ushort*   Wlo    = (ushort*)alloc((size_t)IN_CH * OUT_CH * 2);
  unsigned* gmax   = (unsigned*)alloc(4);
  unsigned* flag   = (unsigned*)alloc(4);

  hipMemsetAsync(cnt,  0, (size_t)n * 4, stream);
  hipMemsetAsync(gmax, 0, 4, stream);
  hipMemsetAsync(flag, 0, 4, stream);

  gat_wprep<<<(IN_CH * OUT_CH + 255) / 256, 256, 0, stream>>>(W, Whi, Wlo);
  gat_gemm_mfma<<<(n + 63) / 64, 256, 0, stream>>>(x, Whi, Wlo, a_src, a_dst, Wh, e, gmax, n);

  gat_detect64<<<1, 256, 0, stream>>>((const unsigned*)eidx, flag, 8192);
  gat_pass1<<<(E + 255) / 256, 256, 0, stream>>>(eidx, flag, cnt, E);
  scan_partial<<<nb, 256, 0, stream>>>(cnt, bsum, n);
  scan_bsum<<<1, 256, 0, stream>>>(bsum, segp, nb, n, E);
  scan_final<<<nb, 256, 0, stream>>>(cnt, bsum, segp, cursor, n);
  if (n <= 65536) {
    gat_scatter<unsigned short><<<(E + 255) / 256, 256, 0, stream>>>(
        eidx, flag, cursor, (unsigned short*)perm, E);
    gat_aggregate<unsigned short><<<(n + 3) / 4, 256, 0, stream>>>(
        Wh, e, gmax, (const unsigned short*)perm, segp, out, n);
  } else {
    gat_scatter<unsigned><<<(E + 255) / 256, 256, 0, stream>>>(
        eidx, flag, cursor, (unsigned*)perm, E);
    gat_aggregate<unsigned><<<(n + 3) / 4, 256, 0, stream>>>(
        Wh, e, gmax, (const unsigned*)perm, segp, out, n);
  }
}

// Round 10
// 199.417 us; speedup vs baseline: 1.8023x; 1.1098x over previous
//
#include <hip/hip_runtime.h>
#include <math.h>

#define IN_CH 256
#define OUT_CH 64
#define SCHUNK 512  // scan elements per block (needs n <= 256*SCHUNK = 131072)

typedef unsigned short ushort;
typedef unsigned short ushort8 __attribute__((ext_vector_type(8)));
typedef __bf16 bf16x8 __attribute__((ext_vector_type(8)));
typedef float f32x4 __attribute__((ext_vector_type(4)));

// ---------- monotonic float<->uint mapping for atomic max ----------
__device__ __forceinline__ unsigned fmap(float f) {
  unsigned u = __float_as_uint(f);
  return (u & 0x80000000u) ? ~u : (u | 0x80000000u);
}
__device__ __forceinline__ float funmap(unsigned u) {
  return (u & 0x80000000u) ? __uint_as_float(u & 0x7fffffffu) : __uint_as_float(~u);
}

__device__ __forceinline__ ushort bf16rne(float v) {
  unsigned u = __float_as_uint(v);
  return (ushort)((u + 0x7FFFu + ((u >> 16) & 1u)) >> 16);
}

// ---------- K0: split W into bf16 hi/lo in MFMA FRAGMENT ORDER ----------
// frag index i = ((ks*4 + ct)*64 + lane)*8 + e  maps to
//   k = ks*32 + (lane>>4)*8 + e ,  col = ct*16 + (lane&15)
// so a wave's B-load for (ks,ct) is one contiguous 1KB chunk.
__global__ __launch_bounds__(256) void gat_wprep(
    const float* __restrict__ W, ushort* __restrict__ Whi, ushort* __restrict__ Wlo)
{
  int i = blockIdx.x * 256 + threadIdx.x;          // 0..16383
  if (i >= IN_CH * OUT_CH) return;
  int e = i & 7, ln = (i >> 3) & 63, ctks = i >> 9;
  int ct = ctks & 3, ks = ctks >> 2;
  int k = ks * 32 + (ln >> 4) * 8 + e;
  int col = ct * 16 + (ln & 15);
  float v = W[(size_t)k * OUT_CH + col];
  unsigned u = __float_as_uint(v);
  unsigned hb = (u + 0x7FFFu + ((u >> 16) & 1u)) & 0xFFFF0000u;  // RNE bf16 as fp32 bits
  Whi[i] = (ushort)(hb >> 16);
  Wlo[i] = bf16rne(v - __uint_as_float(hb));
}

// ---------- K1: Wh = x @ W via split-bf16 MFMA ; e = Wh.(a_src+a_dst) ; gmax ----------
// 512 threads (8 waves), 128 rows/block, wave = one 16-row group.
// All 16 x-loads issued before LDS staging (deep MLP); B-frags from LDS (one barrier total).
// acc = (xh+xl)@(wh+wl) : 4 MFMA per (ks,ct) -> exact split product.
__global__ __launch_bounds__(512) void gat_gemm_mfma(
    const float* __restrict__ x, const ushort* __restrict__ Whi, const ushort* __restrict__ Wlo,
    const float* __restrict__ a_src, const float* __restrict__ a_dst,
    float* __restrict__ Wh, float* __restrict__ e, unsigned* __restrict__ gmax, int n)
{
  __shared__ uint4 Bf[4096];   // 64KB: [0,2048) = hi frags, [2048,4096) = lo frags
  const int tid = threadIdx.x;
  const int lane = tid & 63;
  const int wave = tid >> 6;
  const int row0 = blockIdx.x * 128 + wave * 16;
  const int lg = lane >> 4;              // k-pack group
  const int li = lane & 15;              // row (A) / col (B/D)
  const int kp = lg * 8;

  int arow = row0 + li; if (arow > n - 1) arow = n - 1;   // clamp; stores guarded

  // issue all x loads first (16 outstanding 16B loads per lane)
  const float* __restrict__ xr = x + (size_t)arow * IN_CH + kp;
  float4 xv0[8], xv1[8];
#pragma unroll
  for (int ks = 0; ks < 8; ++ks) {
    xv0[ks] = *(const float4*)(xr + ks * 32);
    xv1[ks] = *(const float4*)(xr + ks * 32 + 4);
  }

  // stage fragment-ordered W into LDS (coalesced uint4)
  {
    const uint4* __restrict__ srcH = (const uint4*)Whi;
    const uint4* __restrict__ srcL = (const uint4*)Wlo;
#pragma unroll
    for (int i = 0; i < 4; ++i) {
      Bf[tid + i * 512]        = srcH[tid + i * 512];
      Bf[2048 + tid + i * 512] = srcL[tid + i * 512];
    }
  }

  float asd[4];
#pragma unroll
  for (int ct = 0; ct < 4; ++ct) {
    int col = ct * 16 + li;
    asd[ct] = a_src[col] + a_dst[col];
  }

  __syncthreads();

  f32x4 acc[4] = {{0.f,0.f,0.f,0.f},{0.f,0.f,0.f,0.f},{0.f,0.f,0.f,0.f},{0.f,0.f,0.f,0.f}};
#pragma unroll
  for (int ks = 0; ks < 8; ++ks) {
    float vv[8] = {xv0[ks].x, xv0[ks].y, xv0[ks].z, xv0[ks].w,
                   xv1[ks].x, xv1[ks].y, xv1[ks].z, xv1[ks].w};
    ushort8 ah_u, al_u;
#pragma unroll
    for (int t = 0; t < 8; ++t) {
      unsigned u = __float_as_uint(vv[t]);
      unsigned hb = (u + 0x7FFFu + ((u >> 16) & 1u)) & 0xFFFF0000u;
      ah_u[t] = (ushort)(hb >> 16);
      al_u[t] = bf16rne(vv[t] - __uint_as_float(hb));
    }
    bf16x8 ah = __builtin_bit_cast(bf16x8, ah_u);
    bf16x8 al = __builtin_bit_cast(bf16x8, al_u);
#pragma unroll
    for (int ct = 0; ct < 4; ++ct) {
      int fo = (ks * 4 + ct) * 64 + lane;
      bf16x8 bh = __builtin_bit_cast(bf16x8, Bf[fo]);
      bf16x8 bl = __builtin_bit_cast(bf16x8, Bf[2048 + fo]);
      acc[ct] = __builtin_amdgcn_mfma_f32_16x16x32_bf16(ah, bh, acc[ct], 0, 0, 0);
      acc[ct] = __builtin_amdgcn_mfma_f32_16x16x32_bf16(al, bh, acc[ct], 0, 0, 0);
      acc[ct] = __builtin_amdgcn_mfma_f32_16x16x32_bf16(ah, bl, acc[ct], 0, 0, 0);
      acc[ct] = __builtin_amdgcn_mfma_f32_16x16x32_bf16(al, bl, acc[ct], 0, 0, 0);
    }
  }

  // store Wh (D layout: row = lg*4 + r, col = ct*16 + li)
#pragma unroll
  for (int ct = 0; ct < 4; ++ct) {
    int col = ct * 16 + li;
#pragma unroll
    for (int r = 0; r < 4; ++r) {
      int row = row0 + lg * 4 + r;
      if (row < n) Wh[(size_t)row * OUT_CH + col] = acc[ct][r];
    }
  }

  // e[row] = sum_col D[row][col]*asd[col] ; gmax = max(e)
  float vmax = -INFINITY;
#pragma unroll
  for (int r = 0; r < 4; ++r) {
    float pe = acc[0][r] * asd[0] + acc[1][r] * asd[1] + acc[2][r] * asd[2] + acc[3][r] * asd[3];
    pe += __shfl_xor(pe, 1); pe += __shfl_xor(pe, 2); pe += __shfl_xor(pe, 4); pe += __shfl_xor(pe, 8);
    int row = row0 + lg * 4 + r;
    if (row < n) {
      if (li == 0) e[row] = pe;
      vmax = fmaxf(vmax, pe);
    }
  }
  vmax = fmaxf(vmax, __shfl_xor(vmax, 16));
  vmax = fmaxf(vmax, __shfl_xor(vmax, 32));
  if (lane == 0) atomicMax(gmax, fmap(vmax));
}

// ---------- K2: detect int64 vs int32 edge_index ----------
__global__ void gat_detect64(const unsigned* __restrict__ eidx, unsigned* __restrict__ flag, int npairs)
{
  unsigned v = 0;
  for (int i = threadIdx.x; i < npairs; i += blockDim.x) v |= eidx[2 * i + 1];
#pragma unroll
  for (int m = 32; m >= 1; m >>= 1) v |= __shfl_xor(v, m);
  if ((threadIdx.x & 63) == 0) atomicOr(flag, v);
}

// ---------- K3: count degrees (reads only the col half of eidx) ----------
__global__ void gat_pass1(
    const void* __restrict__ eidx, const unsigned* __restrict__ flag,
    int* __restrict__ cnt, int E)
{
  int j = blockIdx.x * blockDim.x + threadIdx.x;
  if (j >= E) return;
  int c;
  if (*flag == 0) {  // int64: low word of element E+j
    const unsigned* p = (const unsigned*)eidx;
    c = (int)p[2 * ((size_t)E + j)];
  } else {
    const int* p = (const int*)eidx;
    c = p[(size_t)E + j];
  }
  atomicAdd(cnt + c, 1);
}

// ---------- K4a/b/c: hierarchical exclusive scan of cnt -> segp, cursor ----------
__global__ __launch_bounds__(256) void scan_partial(
    const int* __restrict__ cnt, int* __restrict__ bsum, int n)
{
  int base = blockIdx.x * SCHUNK;
  int tid = threadIdx.x;
  int s = 0;
  int i0 = base + tid, i1 = base + tid + 256;
  if (i0 < n) s += cnt[i0];
  if (i1 < n) s += cnt[i1];
#pragma unroll
  for (int m = 1; m < 64; m <<= 1) s += __shfl_xor(s, m);
  __shared__ int ws[4];
  if ((tid & 63) == 0) ws[tid >> 6] = s;
  __syncthreads();
  if (tid == 0) bsum[blockIdx.x] = ws[0] + ws[1] + ws[2] + ws[3];
}

__global__ __launch_bounds__(256) void scan_bsum(
    int* __restrict__ bsum, int* __restrict__ segp, int nb, int n, int E)
{
  __shared__ int sh[256];
  int tid = threadIdx.x;
  int v = (tid < nb) ? bsum[tid] : 0;
  sh[tid] = v;
  __syncthreads();
  for (int off = 1; off < 256; off <<= 1) {
    int add = (tid >= off) ? sh[tid - off] : 0;
    __syncthreads();
    sh[tid] += add;
    __syncthreads();
  }
  if (tid < nb) bsum[tid] = sh[tid] - v;   // exclusive block offsets
  if (tid == 0) segp[n] = E;
}

__global__ __launch_bounds__(256) void scan_final(
    const int* __restrict__ cnt, const int* __restrict__ bsum,
    int* __restrict__ segp, int* __restrict__ cursor, int n)
{
  int base = blockIdx.x * SCHUNK;
  int tid = threadIdx.x;
  int i0 = base + 2 * tid, i1 = i0 + 1;
  int c0 = (i0 < n) ? cnt[i0] : 0;
  int c1 = (i1 < n) ? cnt[i1] : 0;
  int ps = c0 + c1;
  __shared__ int sh[256];
  sh[tid] = ps;
  __syncthreads();
  for (int off = 1; off < 256; off <<= 1) {
    int add = (tid >= off) ? sh[tid - off] : 0;
    __syncthreads();
    sh[tid] += add;
    __syncthreads();
  }
  int excl = sh[tid] - ps + bsum[blockIdx.x];
  if (i0 < n) { segp[i0] = excl;      cursor[i0] = excl; }
  if (i1 < n) { segp[i1] = excl + c0; cursor[i1] = excl + c0; }
}

// ---------- K5: pure CSR scatter — IDX bytes per edge (row id only) ----------
template <typename IDX>
__global__ void gat_scatter(
    const void* __restrict__ eidx, const unsigned* __restrict__ flag,
    int* __restrict__ cursor, IDX* __restrict__ perm, int E)
{
  int j = blockIdx.x * blockDim.x + threadIdx.x;
  if (j >= E) return;
  int r, c;
  if (*flag == 0) {
    const long long* p = (const long long*)eidx;
    r = (int)p[j]; c = (int)p[(size_t)E + j];
  } else {
    const int* p = (const int*)eidx;
    r = p[j]; c = p[(size_t)E + j];
  }
  int pos = atomicAdd(cursor + c, 1);
  perm[pos] = (IDX)r;
}

// ---------- K6: aggregate + ELU; recompute ev in-loop (1 wave/node, lane=channel) ----------
template <typename IDX>
__global__ __launch_bounds__(256) void gat_aggregate(
    const float* __restrict__ Wh, const float* __restrict__ e,
    const unsigned* __restrict__ gmax, const IDX* __restrict__ perm,
    const int* __restrict__ segp, float* __restrict__ out, int n)
{
  int wave = threadIdx.x >> 6, lane = threadIdx.x & 63;
  int c = blockIdx.x * 4 + wave;
  if (c >= n) return;
  int p0 = segp[c], p1 = segp[c + 1];
  float s = 2.0f * funmap(*gmax);
  float ec = e[c] - s;

  float a0 = 0.f, a1 = 0.f, a2 = 0.f, a3 = 0.f;
  float s0 = 0.f, s1 = 0.f, s2 = 0.f, s3 = 0.f;
  int p = p0;
  for (; p + 4 <= p1; p += 4) {
    unsigned r0 = (unsigned)perm[p],     r1 = (unsigned)perm[p + 1];
    unsigned r2 = (unsigned)perm[p + 2], r3 = (unsigned)perm[p + 3];
    float e0 = e[r0], e1 = e[r1], e2 = e[r2], e3 = e[r3];
    float w0 = Wh[(size_t)r0 * OUT_CH + lane];
    float w1 = Wh[(size_t)r1 * OUT_CH + lane];
    float w2 = Wh[(size_t)r2 * OUT_CH + lane];
    float w3 = Wh[(size_t)r3 * OUT_CH + lane];
    float v0 = __expf(e0 + ec), v1 = __expf(e1 + ec);
    float v2 = __expf(e2 + ec), v3 = __expf(e3 + ec);
    a0 = fmaf(v0, w0, a0); s0 += v0;
    a1 = fmaf(v1, w1, a1); s1 += v1;
    a2 = fmaf(v2, w2, a2); s2 += v2;
    a3 = fmaf(v3, w3, a3); s3 += v3;
  }
  for (; p < p1; ++p) {
    unsigned r = (unsigned)perm[p];
    float v = __expf(e[r] + ec);
    a0 = fmaf(v, Wh[(size_t)r * OUT_CH + lane], a0); s0 += v;
  }
  float acc = (a0 + a1) + (a2 + a3);
  float ssum = (s0 + s1) + (s2 + s3);
  float rden = (p1 > p0) ? 1.0f / ssum : 0.0f;  // empty segment -> elu(0)=0
  acc *= rden;
  out[(size_t)c * OUT_CH + lane] = acc > 0.f ? acc : expm1f(acc);
}

extern "C" void kernel_launch(void* const* d_in, const int* in_sizes, int n_in,
                              void* d_out, int out_size, void* d_ws, size_t ws_size,
                              hipStream_t stream)
{
  const float* x     = (const float*)d_in[0];
  const void*  eidx  = d_in[1];
  const float* W     = (const float*)d_in[2];
  const float* a_src = (const float*)d_in[3];
  const float* a_dst = (const float*)d_in[4];
  float* out = (float*)d_out;

  const int n = in_sizes[0] / IN_CH;   // 50000
  const int E = in_sizes[1] / 2;       // 800000
  const int nb = (n + SCHUNK - 1) / SCHUNK;

  char* ws = (char*)d_ws;
  size_t off = 0;
  auto alloc = [&](size_t bytes) -> void* {
    void* p = ws + off;
    off = (off + bytes + 255) & ~(size_t)255;
    return p;
  };
  float*    Wh     = (float*)alloc((size_t)n * OUT_CH * 4);
  float*    e      = (float*)alloc((size_t)n * 4);
  void*     perm   = alloc((size_t)E * 4);   // ushort or uint, by n
  int*      cnt    = (int*)alloc((size_t)n * 4);
  int*      segp   = (int*)alloc((size_t)(n + 1) * 4);
  int*      cursor = (int*)alloc((size_t)n * 4);
  int*      bsum   = (int*)alloc((size_t)nb * 4);
  ushort*   Whi    = (ushort*)alloc((size_t)IN_CH * OUT_CH * 2);
  ushort*   Wlo    = (ushort*)alloc((size_t)IN_CH * OUT_CH * 2);
  unsigned* gmax   = (unsigned*)alloc(4);
  unsigned* flag   = (unsigned*)alloc(4);

  hipMemsetAsync(cnt,  0, (size_t)n * 4, stream);
  hipMemsetAsync(gmax, 0, 4, stream);
  hipMemsetAsync(flag, 0, 4, stream);

  gat_wprep<<<(IN_CH * OUT_CH + 255) / 256, 256, 0, stream>>>(W, Whi, Wlo);
  gat_gemm_mfma<<<(n + 127) / 128, 512, 0, stream>>>(x, Whi, Wlo, a_src, a_dst, Wh, e, gmax, n);

  gat_detect64<<<1, 256, 0, stream>>>((const unsigned*)eidx, flag, 8192);
  gat_pass1<<<(E + 255) / 256, 256, 0, stream>>>(eidx, flag, cnt, E);
  scan_partial<<<nb, 256, 0, stream>>>(cnt, bsum, n);
  scan_bsum<<<1, 256, 0, stream>>>(bsum, segp, nb, n, E);
  scan_final<<<nb, 256, 0, stream>>>(cnt, bsum, segp, cursor, n);
  if (n <= 65536) {
    gat_scatter<unsigned short><<<(E + 255) / 256, 256, 0, stream>>>(
        eidx, flag, cursor, (unsigned short*)perm, E);
    gat_aggregate<unsigned short><<<(n + 3) / 4, 256, 0, stream>>>(
        Wh, e, gmax, (const unsigned short*)perm, segp, out, n);
  } else {
    gat_scatter<unsigned><<<(E + 255) / 256, 256, 0, stream>>>(
        eidx, flag, cursor, (unsigned*)perm, E);
    gat_aggregate<unsigned><<<(n + 3) / 4, 256, 0, stream>>>(
        Wh, e, gmax, (const unsigned*)perm, segp, out, n);
  }
}

// Round 11
// 193.901 us; speedup vs baseline: 1.8536x; 1.0284x over previous
//
#include <hip/hip_runtime.h>
#include <math.h>

#define IN_CH 256
#define OUT_CH 64
#define SCHUNK 512  // scan elements per block (needs n <= 256*SCHUNK = 131072)

typedef unsigned short ushort;
typedef unsigned short ushort8 __attribute__((ext_vector_type(8)));
typedef __bf16 bf16x8 __attribute__((ext_vector_type(8)));
typedef float f32x4 __attribute__((ext_vector_type(4)));

// ---------- monotonic float<->uint mapping for atomic max ----------
__device__ __forceinline__ unsigned fmap(float f) {
  unsigned u = __float_as_uint(f);
  return (u & 0x80000000u) ? ~u : (u | 0x80000000u);
}
__device__ __forceinline__ float funmap(unsigned u) {
  return (u & 0x80000000u) ? __uint_as_float(u & 0x7fffffffu) : __uint_as_float(~u);
}

__device__ __forceinline__ ushort bf16rne(float v) {
  unsigned u = __float_as_uint(v);
  return (ushort)((u + 0x7FFFu + ((u >> 16) & 1u)) >> 16);
}

// ---------- K0: split W into bf16 hi/lo in MFMA FRAGMENT ORDER ----------
// frag index i = ((ks*4 + ct)*64 + lane)*8 + e  maps to
//   k = ks*32 + (lane>>4)*8 + e ,  col = ct*16 + (lane&15)
// so a wave's B-load for (ks,ct) is one contiguous 1KB chunk.
__global__ __launch_bounds__(256) void gat_wprep(
    const float* __restrict__ W, ushort* __restrict__ Whi, ushort* __restrict__ Wlo)
{
  int i = blockIdx.x * 256 + threadIdx.x;          // 0..16383
  if (i >= IN_CH * OUT_CH) return;
  int e = i & 7, ln = (i >> 3) & 63, ctks = i >> 9;
  int ct = ctks & 3, ks = ctks >> 2;
  int k = ks * 32 + (ln >> 4) * 8 + e;
  int col = ct * 16 + (ln & 15);
  float v = W[(size_t)k * OUT_CH + col];
  unsigned u = __float_as_uint(v);
  unsigned hb = (u + 0x7FFFu + ((u >> 16) & 1u)) & 0xFFFF0000u;  // RNE bf16 as fp32 bits
  Whi[i] = (ushort)(hb >> 16);
  Wlo[i] = bf16rne(v - __uint_as_float(hb));
}

// ---------- K1: Wh = x @ W via split-bf16 MFMA ; e = Wh.(a_src+a_dst) ; gmax ----------
// Col-split waves: block = 4 waves (wave = one 16-col tile ct) x 32 rows (2 rgroups).
// W fragments live in 64 VGPRs per wave (hi+lo, 8 k-slices) -> no W staging, no LDS tile.
// x read directly from global; 4 ct-waves of a block share rows via L2.
// e needs a cross-wave (column) reduction -> tiny ep[4][32] LDS + one barrier.
__global__ __launch_bounds__(256, 4) void gat_gemm_mfma(
    const float* __restrict__ x, const ushort* __restrict__ Whi, const ushort* __restrict__ Wlo,
    const float* __restrict__ a_src, const float* __restrict__ a_dst,
    float* __restrict__ Wh, float* __restrict__ e, unsigned* __restrict__ gmax, int n)
{
  __shared__ float ep[4][32];
  const int tid = threadIdx.x;
  const int lane = tid & 63;
  const int ct = tid >> 6;             // wave id = column tile
  const int lg = lane >> 4;            // k-pack group
  const int li = lane & 15;            // row (A) / col (B/D)
  const int row0 = blockIdx.x * 32;

  // my ct's W fragments: hi+lo for all 8 k-slices = 64 VGPRs (L2-hot, independent loads)
  bf16x8 wh[8], wl[8];
#pragma unroll
  for (int ks = 0; ks < 8; ++ks) {
    int fo = (ks * 4 + ct) * 64 + lane;
    wh[ks] = __builtin_bit_cast(bf16x8, ((const uint4*)Whi)[fo]);
    wl[ks] = __builtin_bit_cast(bf16x8, ((const uint4*)Wlo)[fo]);
  }
  const int col = ct * 16 + li;
  const float asd = a_src[col] + a_dst[col];

  f32x4 accA = {0.f,0.f,0.f,0.f}, accB = {0.f,0.f,0.f,0.f};
#pragma unroll
  for (int rg = 0; rg < 2; ++rg) {
    f32x4 acc = {0.f,0.f,0.f,0.f};
    int arow = row0 + rg * 16 + li; if (arow > n - 1) arow = n - 1;  // clamp; stores guarded
    const float* __restrict__ xr = x + (size_t)arow * IN_CH + lg * 8;
#pragma unroll
    for (int ks = 0; ks < 8; ++ks) {
      float4 v0 = *(const float4*)(xr + ks * 32);
      float4 v1 = *(const float4*)(xr + ks * 32 + 4);
      float vv[8] = {v0.x, v0.y, v0.z, v0.w, v1.x, v1.y, v1.z, v1.w};
      ushort8 ah_u, al_u;
#pragma unroll
      for (int t = 0; t < 8; ++t) {
        unsigned u = __float_as_uint(vv[t]);
        unsigned hb = (u + 0x7FFFu + ((u >> 16) & 1u)) & 0xFFFF0000u;
        ah_u[t] = (ushort)(hb >> 16);
        al_u[t] = bf16rne(vv[t] - __uint_as_float(hb));
      }
      bf16x8 ah = __builtin_bit_cast(bf16x8, ah_u);
      bf16x8 al = __builtin_bit_cast(bf16x8, al_u);
      acc = __builtin_amdgcn_mfma_f32_16x16x32_bf16(ah, wh[ks], acc, 0, 0, 0);
      acc = __builtin_amdgcn_mfma_f32_16x16x32_bf16(al, wh[ks], acc, 0, 0, 0);
      acc = __builtin_amdgcn_mfma_f32_16x16x32_bf16(ah, wl[ks], acc, 0, 0, 0);
      acc = __builtin_amdgcn_mfma_f32_16x16x32_bf16(al, wl[ks], acc, 0, 0, 0);
    }
    if (rg == 0) accA = acc; else accB = acc;
  }

  // store Wh (D: row = rg*16 + lg*4 + r, col = ct*16 + li) + per-ct e partials
#pragma unroll
  for (int rg = 0; rg < 2; ++rg) {
    f32x4 acc = rg ? accB : accA;
#pragma unroll
    for (int r = 0; r < 4; ++r) {
      int row = row0 + rg * 16 + lg * 4 + r;
      if (row < n) Wh[(size_t)row * OUT_CH + col] = acc[r];
      float pe = acc[r] * asd;
      pe += __shfl_xor(pe, 1); pe += __shfl_xor(pe, 2);
      pe += __shfl_xor(pe, 4); pe += __shfl_xor(pe, 8);
      if (li == 0) ep[ct][rg * 16 + lg * 4 + r] = pe;   // lanes 0,16,32,48
    }
  }
  __syncthreads();

  // wave 0, lanes 0..31: sum the 4 ct partials per row, write e, track max
  if (tid < 32) {
    int row = row0 + tid;
    float pe = ep[0][tid] + ep[1][tid] + ep[2][tid] + ep[3][tid];
    float vmax = -INFINITY;
    if (row < n) { e[row] = pe; vmax = pe; }
    vmax = fmaxf(vmax, __shfl_xor(vmax, 1));
    vmax = fmaxf(vmax, __shfl_xor(vmax, 2));
    vmax = fmaxf(vmax, __shfl_xor(vmax, 4));
    vmax = fmaxf(vmax, __shfl_xor(vmax, 8));
    vmax = fmaxf(vmax, __shfl_xor(vmax, 16));
    if (tid == 0) atomicMax(gmax, fmap(vmax));
  }
}

// ---------- K2: detect int64 vs int32 edge_index ----------
__global__ void gat_detect64(const unsigned* __restrict__ eidx, unsigned* __restrict__ flag, int npairs)
{
  unsigned v = 0;
  for (int i = threadIdx.x; i < npairs; i += blockDim.x) v |= eidx[2 * i + 1];
#pragma unroll
  for (int m = 32; m >= 1; m >>= 1) v |= __shfl_xor(v, m);
  if ((threadIdx.x & 63) == 0) atomicOr(flag, v);
}

// ---------- K3: count degrees (reads only the col half of eidx) ----------
__global__ void gat_pass1(
    const void* __restrict__ eidx, const unsigned* __restrict__ flag,
    int* __restrict__ cnt, int E)
{
  int j = blockIdx.x * blockDim.x + threadIdx.x;
  if (j >= E) return;
  int c;
  if (*flag == 0) {  // int64: low word of element E+j
    const unsigned* p = (const unsigned*)eidx;
    c = (int)p[2 * ((size_t)E + j)];
  } else {
    const int* p = (const int*)eidx;
    c = p[(size_t)E + j];
  }
  atomicAdd(cnt + c, 1);
}

// ---------- K4a/b/c: hierarchical exclusive scan of cnt -> segp, cursor ----------
__global__ __launch_bounds__(256) void scan_partial(
    const int* __restrict__ cnt, int* __restrict__ bsum, int n)
{
  int base = blockIdx.x * SCHUNK;
  int tid = threadIdx.x;
  int s = 0;
  int i0 = base + tid, i1 = base + tid + 256;
  if (i0 < n) s += cnt[i0];
  if (i1 < n) s += cnt[i1];
#pragma unroll
  for (int m = 1; m < 64; m <<= 1) s += __shfl_xor(s, m);
  __shared__ int ws[4];
  if ((tid & 63) == 0) ws[tid >> 6] = s;
  __syncthreads();
  if (tid == 0) bsum[blockIdx.x] = ws[0] + ws[1] + ws[2] + ws[3];
}

__global__ __launch_bounds__(256) void scan_bsum(
    int* __restrict__ bsum, int* __restrict__ segp, int nb, int n, int E)
{
  __shared__ int sh[256];
  int tid = threadIdx.x;
  int v = (tid < nb) ? bsum[tid] : 0;
  sh[tid] = v;
  __syncthreads();
  for (int off = 1; off < 256; off <<= 1) {
    int add = (tid >= off) ? sh[tid - off] : 0;
    __syncthreads();
    sh[tid] += add;
    __syncthreads();
  }
  if (tid < nb) bsum[tid] = sh[tid] - v;   // exclusive block offsets
  if (tid == 0) segp[n] = E;
}

__global__ __launch_bounds__(256) void scan_final(
    const int* __restrict__ cnt, const int* __restrict__ bsum,
    int* __restrict__ segp, int* __restrict__ cursor, int n)
{
  int base = blockIdx.x * SCHUNK;
  int tid = threadIdx.x;
  int i0 = base + 2 * tid, i1 = i0 + 1;
  int c0 = (i0 < n) ? cnt[i0] : 0;
  int c1 = (i1 < n) ? cnt[i1] : 0;
  int ps = c0 + c1;
  __shared__ int sh[256];
  sh[tid] = ps;
  __syncthreads();
  for (int off = 1; off < 256; off <<= 1) {
    int add = (tid >= off) ? sh[tid - off] : 0;
    __syncthreads();
    sh[tid] += add;
    __syncthreads();
  }
  int excl = sh[tid] - ps + bsum[blockIdx.x];
  if (i0 < n) { segp[i0] = excl;      cursor[i0] = excl; }
  if (i1 < n) { segp[i1] = excl + c0; cursor[i1] = excl + c0; }
}

// ---------- K5: pure CSR scatter — IDX bytes per edge (row id only) ----------
template <typename IDX>
__global__ void gat_scatter(
    const void* __restrict__ eidx, const unsigned* __restrict__ flag,
    int* __restrict__ cursor, IDX* __restrict__ perm, int E)
{
  int j = blockIdx.x * blockDim.x + threadIdx.x;
  if (j >= E) return;
  int r, c;
  if (*flag == 0) {
    const long long* p = (const long long*)eidx;
    r = (int)p[j]; c = (int)p[(size_t)E + j];
  } else {
    const int* p = (const int*)eidx;
    r = p[j]; c = p[(size_t)E + j];
  }
  int pos = atomicAdd(cursor + c, 1);
  perm[pos] = (IDX)r;
}

// ---------- K6: aggregate + ELU; recompute ev in-loop (1 wave/node, lane=channel) ----------
template <typename IDX>
__global__ __launch_bounds__(256) void gat_aggregate(
    const float* __restrict__ Wh, const float* __restrict__ e,
    const unsigned* __restrict__ gmax, const IDX* __restrict__ perm,
    const int* __restrict__ segp, float* __restrict__ out, int n)
{
  int wave = threadIdx.x >> 6, lane = threadIdx.x & 63;
  int c = blockIdx.x * 4 + wave;
  if (c >= n) return;
  int p0 = segp[c], p1 = segp[c + 1];
  float s = 2.0f * funmap(*gmax);
  float ec = e[c] - s;

  float a0 = 0.f, a1 = 0.f, a2 = 0.f, a3 = 0.f;
  float s0 = 0.f, s1 = 0.f, s2 = 0.f, s3 = 0.f;
  int p = p0;
  for (; p + 4 <= p1; p += 4) {
    unsigned r0 = (unsigned)perm[p],     r1 = (unsigned)perm[p + 1];
    unsigned r2 = (unsigned)perm[p + 2], r3 = (unsigned)perm[p + 3];
    float e0 = e[r0], e1 = e[r1], e2 = e[r2], e3 = e[r3];
    float w0 = Wh[(size_t)r0 * OUT_CH + lane];
    float w1 = Wh[(size_t)r1 * OUT_CH + lane];
    float w2 = Wh[(size_t)r2 * OUT_CH + lane];
    float w3 = Wh[(size_t)r3 * OUT_CH + lane];
    float v0 = __expf(e0 + ec), v1 = __expf(e1 + ec);
    float v2 = __expf(e2 + ec), v3 = __expf(e3 + ec);
    a0 = fmaf(v0, w0, a0); s0 += v0;
    a1 = fmaf(v1, w1, a1); s1 += v1;
    a2 = fmaf(v2, w2, a2); s2 += v2;
    a3 = fmaf(v3, w3, a3); s3 += v3;
  }
  for (; p < p1; ++p) {
    unsigned r = (unsigned)perm[p];
    float v = __expf(e[r] + ec);
    a0 = fmaf(v, Wh[(size_t)r * OUT_CH + lane], a0); s0 += v;
  }
  float acc = (a0 + a1) + (a2 + a3);
  float ssum = (s0 + s1) + (s2 + s3);
  float rden = (p1 > p0) ? 1.0f / ssum : 0.0f;  // empty segment -> elu(0)=0
  acc *= rden;
  out[(size_t)c * OUT_CH + lane] = acc > 0.f ? acc : expm1f(acc);
}

extern "C" void kernel_launch(void* const* d_in, const int* in_sizes, int n_in,
                              void* d_out, int out_size, void* d_ws, size_t ws_size,
                              hipStream_t stream)
{
  const float* x     = (const float*)d_in[0];
  const void*  eidx  = d_in[1];
  const float* W     = (const float*)d_in[2];
  const float* a_src = (const float*)d_in[3];
  const float* a_dst = (const float*)d_in[4];
  float* out = (float*)d_out;

  const int n = in_sizes[0] / IN_CH;   // 50000
  const int E = in_sizes[1] / 2;       // 800000
  const int nb = (n + SCHUNK - 1) / SCHUNK;

  char* ws = (char*)d_ws;
  size_t off = 0;
  auto alloc = [&](size_t bytes) -> void* {
    void* p = ws + off;
    off = (off + bytes + 255) & ~(size_t)255;
    return p;
  };
  float*    Wh     = (float*)alloc((size_t)n * OUT_CH * 4);
  float*    e      = (float*)alloc((size_t)n * 4);
  void*     perm   = alloc((size_t)E * 4);   // ushort or uint, by n
  int*      cnt    = (int*)alloc((size_t)n * 4);
  int*      segp   = (int*)alloc((size_t)(n + 1) * 4);
  int*      cursor = (int*)alloc((size_t)n * 4);
  int*      bsum   = (int*)alloc((size_t)nb * 4);
  ushort*   Whi    = (ushort*)alloc((size_t)IN_CH * OUT_CH * 2);
  ushort*   Wlo    = (ushort*)alloc((size_t)IN_CH * OUT_CH * 2);
  unsigned* gmax   = (unsigned*)alloc(4);
  unsigned* flag   = (unsigned*)alloc(4);

  hipMemsetAsync(cnt,  0, (size_t)n * 4, stream);
  hipMemsetAsync(gmax, 0, 4, stream);
  hipMemsetAsync(flag, 0, 4, stream);

  gat_wprep<<<(IN_CH * OUT_CH + 255) / 256, 256, 0, stream>>>(W, Whi, Wlo);
  gat_gemm_mfma<<<(n + 31) / 32, 256, 0, stream>>>(x, Whi, Wlo, a_src, a_dst, Wh, e, gmax, n);

  gat_detect64<<<1, 256, 0, stream>>>((const unsigned*)eidx, flag, 8192);
  gat_pass1<<<(E + 255) / 256, 256, 0, stream>>>(eidx, flag, cnt, E);
  scan_partial<<<nb, 256, 0, stream>>>(cnt, bsum, n);
  scan_bsum<<<1, 256, 0, stream>>>(bsum, segp, nb, n, E);
  scan_final<<<nb, 256, 0, stream>>>(cnt, bsum, segp, cursor, n);
  if (n <= 65536) {
    gat_scatter<unsigned short><<<(E + 255) / 256, 256, 0, stream>>>(
        eidx, flag, cursor, (unsigned short*)perm, E);
    gat_aggregate<unsigned short><<<(n + 3) / 4, 256, 0, stream>>>(
        Wh, e, gmax, (const unsigned short*)perm, segp, out, n);
  } else {
    gat_scatter<unsigned><<<(E + 255) / 256, 256, 0, stream>>>(
        eidx, flag, cursor, (unsigned*)perm, E);
    gat_aggregate<unsigned><<<(n + 3) / 4, 256, 0, stream>>>(
        Wh, e, gmax, (const unsigned*)perm, segp, out, n);
  }
}

// Round 12
// 157.191 us; speedup vs baseline: 2.2865x; 1.2335x over previous
//
#include <hip/hip_runtime.h>
#include <math.h>

#define IN_CH 256
#define OUT_CH 64
#define SCHUNK 512  // scan elements per block (needs n <= 256*SCHUNK = 131072)

typedef unsigned short ushort;
typedef unsigned short ushort8 __attribute__((ext_vector_type(8)));
typedef unsigned int uint32x4 __attribute__((ext_vector_type(4)));
typedef __bf16 bf16x8 __attribute__((ext_vector_type(8)));
typedef float f32x4 __attribute__((ext_vector_type(4)));

// ---------- monotonic float<->uint mapping for atomic max ----------
__device__ __forceinline__ unsigned fmap(float f) {
  unsigned u = __float_as_uint(f);
  return (u & 0x80000000u) ? ~u : (u | 0x80000000u);
}
__device__ __forceinline__ float funmap(unsigned u) {
  return (u & 0x80000000u) ? __uint_as_float(u & 0x7fffffffu) : __uint_as_float(~u);
}

__device__ __forceinline__ ushort bf16rne(float v) {
  unsigned u = __float_as_uint(v);
  return (ushort)((u + 0x7FFFu + ((u >> 16) & 1u)) >> 16);
}

// ---------- K0: split W into bf16 hi/lo in MFMA FRAGMENT ORDER ----------
// frag index i = ((ks*4 + ct)*64 + lane)*8 + e  maps to
//   k = ks*32 + (lane>>4)*8 + e ,  col = ct*16 + (lane&15)
__global__ __launch_bounds__(256) void gat_wprep(
    const float* __restrict__ W, ushort* __restrict__ Whi, ushort* __restrict__ Wlo)
{
  int i = blockIdx.x * 256 + threadIdx.x;          // 0..16383
  if (i >= IN_CH * OUT_CH) return;
  int e = i & 7, ln = (i >> 3) & 63, ctks = i >> 9;
  int ct = ctks & 3, ks = ctks >> 2;
  int k = ks * 32 + (ln >> 4) * 8 + e;
  int col = ct * 16 + (ln & 15);
  float v = W[(size_t)k * OUT_CH + col];
  unsigned u = __float_as_uint(v);
  unsigned hb = u & 0xFFFF0000u;                   // truncation split (lo absorbs error)
  Whi[i] = (ushort)(hb >> 16);
  Wlo[i] = bf16rne(v - __uint_as_float(hb));
}

// ---------- K1: Wh = x @ W via split-bf16 MFMA ; e = Wh.(a_src+a_dst) ; gmax ----------
// Col-split waves: block = 4 waves (wave = 16-col tile ct) x 32 rows (2 rgroups).
// Whi fragments in 32 VGPRs; Wlo fragments in 32KB LDS (5 blocks/CU -> ~62% occ).
// Truncation split for x: hi = AND, pack = shr+and_or; lo = sub + bf16 cast (cvt_pk).
__global__ __launch_bounds__(256, 4) void gat_gemm_mfma(
    const float* __restrict__ x, const ushort* __restrict__ Whi, const ushort* __restrict__ Wlo,
    const float* __restrict__ a_src, const float* __restrict__ a_dst,
    float* __restrict__ Wh, float* __restrict__ e, unsigned* __restrict__ gmax, int n)
{
  __shared__ uint4 Blo[2048];                      // 32KB lo frags; reused as ep after barrier
  const int tid = threadIdx.x;
  const int lane = tid & 63;
  const int ct = tid >> 6;             // wave id = column tile
  const int lg = lane >> 4;            // k-pack group
  const int li = lane & 15;            // row (A) / col (B/D)
  const int row0 = blockIdx.x * 32;

  // stage Wlo fragments (coalesced uint4)
#pragma unroll
  for (int i = 0; i < 8; ++i) Blo[tid + i * 256] = ((const uint4*)Wlo)[tid + i * 256];

  // my ct's Whi fragments: 32 VGPRs (L2-hot, independent loads)
  bf16x8 wh[8];
#pragma unroll
  for (int ks = 0; ks < 8; ++ks)
    wh[ks] = __builtin_bit_cast(bf16x8, ((const uint4*)Whi)[(ks * 4 + ct) * 64 + lane]);

  const int col = ct * 16 + li;
  const float asd = a_src[col] + a_dst[col];
  __syncthreads();

  f32x4 accA = {0.f,0.f,0.f,0.f}, accB = {0.f,0.f,0.f,0.f};
#pragma unroll
  for (int rg = 0; rg < 2; ++rg) {
    f32x4 acc = {0.f,0.f,0.f,0.f};
    int arow = row0 + rg * 16 + li; if (arow > n - 1) arow = n - 1;  // clamp; stores guarded
    const float* __restrict__ xr = x + (size_t)arow * IN_CH + lg * 8;
#pragma unroll
    for (int ks = 0; ks < 8; ++ks) {
      float4 v0 = *(const float4*)(xr + ks * 32);
      float4 v1 = *(const float4*)(xr + ks * 32 + 4);
      unsigned b0 = __float_as_uint(v0.x), b1 = __float_as_uint(v0.y);
      unsigned b2 = __float_as_uint(v0.z), b3 = __float_as_uint(v0.w);
      unsigned b4 = __float_as_uint(v1.x), b5 = __float_as_uint(v1.y);
      unsigned b6 = __float_as_uint(v1.z), b7 = __float_as_uint(v1.w);
      uint32x4 hv = { (b1 & 0xFFFF0000u) | (b0 >> 16),
                      (b3 & 0xFFFF0000u) | (b2 >> 16),
                      (b5 & 0xFFFF0000u) | (b4 >> 16),
                      (b7 & 0xFFFF0000u) | (b6 >> 16) };
      bf16x8 ah = __builtin_bit_cast(bf16x8, hv);
      float l0 = v0.x - __uint_as_float(b0 & 0xFFFF0000u);
      float l1 = v0.y - __uint_as_float(b1 & 0xFFFF0000u);
      float l2 = v0.z - __uint_as_float(b2 & 0xFFFF0000u);
      float l3 = v0.w - __uint_as_float(b3 & 0xFFFF0000u);
      float l4 = v1.x - __uint_as_float(b4 & 0xFFFF0000u);
      float l5 = v1.y - __uint_as_float(b5 & 0xFFFF0000u);
      float l6 = v1.z - __uint_as_float(b6 & 0xFFFF0000u);
      float l7 = v1.w - __uint_as_float(b7 & 0xFFFF0000u);
      bf16x8 al = { (__bf16)l0, (__bf16)l1, (__bf16)l2, (__bf16)l3,
                    (__bf16)l4, (__bf16)l5, (__bf16)l6, (__bf16)l7 };
      bf16x8 wl = __builtin_bit_cast(bf16x8, Blo[(ks * 4 + ct) * 64 + lane]);
      acc = __builtin_amdgcn_mfma_f32_16x16x32_bf16(ah, wh[ks], acc, 0, 0, 0);
      acc = __builtin_amdgcn_mfma_f32_16x16x32_bf16(al, wh[ks], acc, 0, 0, 0);
      acc = __builtin_amdgcn_mfma_f32_16x16x32_bf16(ah, wl, acc, 0, 0, 0);
      acc = __builtin_amdgcn_mfma_f32_16x16x32_bf16(al, wl, acc, 0, 0, 0);
    }
    if (rg == 0) accA = acc; else accB = acc;
  }
  __syncthreads();                      // Blo reads done; safe to reuse LDS as ep
  float* ep = (float*)Blo;              // ep[ct*32 + idx]

  // store Wh (D: row = rg*16 + lg*4 + r, col) + per-ct e partials
#pragma unroll
  for (int rg = 0; rg < 2; ++rg) {
    f32x4 acc = rg ? accB : accA;
#pragma unroll
    for (int r = 0; r < 4; ++r) {
      int row = row0 + rg * 16 + lg * 4 + r;
      if (row < n) Wh[(size_t)row * OUT_CH + col] = acc[r];
      float pe = acc[r] * asd;
      pe += __shfl_xor(pe, 1); pe += __shfl_xor(pe, 2);
      pe += __shfl_xor(pe, 4); pe += __shfl_xor(pe, 8);
      if (li == 0) ep[ct * 32 + rg * 16 + lg * 4 + r] = pe;   // lanes 0,16,32,48
    }
  }
  __syncthreads();

  // wave 0, lanes 0..31: sum the 4 ct partials per row, write e, track max
  if (tid < 32) {
    int row = row0 + tid;
    float pe = ep[0 * 32 + tid] + ep[1 * 32 + tid] + ep[2 * 32 + tid] + ep[3 * 32 + tid];
    float vmax = -INFINITY;
    if (row < n) { e[row] = pe; vmax = pe; }
    vmax = fmaxf(vmax, __shfl_xor(vmax, 1));
    vmax = fmaxf(vmax, __shfl_xor(vmax, 2));
    vmax = fmaxf(vmax, __shfl_xor(vmax, 4));
    vmax = fmaxf(vmax, __shfl_xor(vmax, 8));
    vmax = fmaxf(vmax, __shfl_xor(vmax, 16));
    if (tid == 0) atomicMax(gmax, fmap(vmax));
  }
}

// ---------- K2: detect int64 vs int32 edge_index ----------
__global__ void gat_detect64(const unsigned* __restrict__ eidx, unsigned* __restrict__ flag, int npairs)
{
  unsigned v = 0;
  for (int i = threadIdx.x; i < npairs; i += blockDim.x) v |= eidx[2 * i + 1];
#pragma unroll
  for (int m = 32; m >= 1; m >>= 1) v |= __shfl_xor(v, m);
  if ((threadIdx.x & 63) == 0) atomicOr(flag, v);
}

// ---------- K3: decode edges, count degrees, emit packed rc + rank ----------
// rank = atomicAdd return value -> the scatter needs NO atomics.
template <typename IDX>
__global__ void gat_pass1(
    const void* __restrict__ eidx, const unsigned* __restrict__ flag,
    int* __restrict__ cnt, void* __restrict__ rcbuf, IDX* __restrict__ rank, int E)
{
  int j = blockIdx.x * blockDim.x + threadIdx.x;
  if (j >= E) return;
  int r, c;
  if (*flag == 0) {  // int64 layout
    const long long* p = (const long long*)eidx;
    r = (int)p[j]; c = (int)p[(size_t)E + j];
  } else {           // int32 layout
    const int* p = (const int*)eidx;
    r = p[j]; c = p[(size_t)E + j];
  }
  int rk = atomicAdd(cnt + c, 1);
  if constexpr (sizeof(IDX) == 2) {
    ((unsigned*)rcbuf)[j] = ((unsigned)c << 16) | (unsigned)r;
  } else {
    ((uint2*)rcbuf)[j] = make_uint2((unsigned)r, (unsigned)c);
  }
  rank[j] = (IDX)rk;
}

// ---------- K4a/b/c: hierarchical exclusive scan of cnt -> segp ----------
__global__ __launch_bounds__(256) void scan_partial(
    const int* __restrict__ cnt, int* __restrict__ bsum, int n)
{
  int base = blockIdx.x * SCHUNK;
  int tid = threadIdx.x;
  int s = 0;
  int i0 = base + tid, i1 = base + tid + 256;
  if (i0 < n) s += cnt[i0];
  if (i1 < n) s += cnt[i1];
#pragma unroll
  for (int m = 1; m < 64; m <<= 1) s += __shfl_xor(s, m);
  __shared__ int ws[4];
  if ((tid & 63) == 0) ws[tid >> 6] = s;
  __syncthreads();
  if (tid == 0) bsum[blockIdx.x] = ws[0] + ws[1] + ws[2] + ws[3];
}

__global__ __launch_bounds__(256) void scan_bsum(
    int* __restrict__ bsum, int* __restrict__ segp, int nb, int n, int E)
{
  __shared__ int sh[256];
  int tid = threadIdx.x;
  int v = (tid < nb) ? bsum[tid] : 0;
  sh[tid] = v;
  __syncthreads();
  for (int off = 1; off < 256; off <<= 1) {
    int add = (tid >= off) ? sh[tid - off] : 0;
    __syncthreads();
    sh[tid] += add;
    __syncthreads();
  }
  if (tid < nb) bsum[tid] = sh[tid] - v;   // exclusive block offsets
  if (tid == 0) segp[n] = E;
}

__global__ __launch_bounds__(256) void scan_final(
    const int* __restrict__ cnt, const int* __restrict__ bsum,
    int* __restrict__ segp, int n)
{
  int base = blockIdx.x * SCHUNK;
  int tid = threadIdx.x;
  int i0 = base + 2 * tid, i1 = i0 + 1;
  int c0 = (i0 < n) ? cnt[i0] : 0;
  int c1 = (i1 < n) ? cnt[i1] : 0;
  int ps = c0 + c1;
  __shared__ int sh[256];
  sh[tid] = ps;
  __syncthreads();
  for (int off = 1; off < 256; off <<= 1) {
    int add = (tid >= off) ? sh[tid - off] : 0;
    __syncthreads();
    sh[tid] += add;
    __syncthreads();
  }
  int excl = sh[tid] - ps + bsum[blockIdx.x];
  if (i0 < n) segp[i0] = excl;
  if (i1 < n) segp[i1] = excl + c0;
}

// ---------- K5: atomic-free CSR scatter: perm[segp[c]+rank] = r ----------
template <typename IDX>
__global__ void gat_scatter(
    const void* __restrict__ rcbuf, const IDX* __restrict__ rank,
    const int* __restrict__ segp, IDX* __restrict__ perm, int E)
{
  int j = blockIdx.x * blockDim.x + threadIdx.x;
  if (j >= E) return;
  unsigned r, c;
  if constexpr (sizeof(IDX) == 2) {
    unsigned p = ((const unsigned*)rcbuf)[j];
    r = p & 0xFFFFu; c = p >> 16;
  } else {
    uint2 p = ((const uint2*)rcbuf)[j];
    r = p.x; c = p.y;
  }
  perm[segp[c] + (int)rank[j]] = (IDX)r;
}

// ---------- K6: aggregate + ELU; recompute ev in-loop (1 wave/node, lane=channel) ----------
template <typename IDX>
__global__ __launch_bounds__(256) void gat_aggregate(
    const float* __restrict__ Wh, const float* __restrict__ e,
    const unsigned* __restrict__ gmax, const IDX* __restrict__ perm,
    const int* __restrict__ segp, float* __restrict__ out, int n)
{
  int wave = threadIdx.x >> 6, lane = threadIdx.x & 63;
  int c = blockIdx.x * 4 + wave;
  if (c >= n) return;
  int p0 = segp[c], p1 = segp[c + 1];
  float s = 2.0f * funmap(*gmax);
  float ec = e[c] - s;

  float a0 = 0.f, a1 = 0.f, a2 = 0.f, a3 = 0.f;
  float s0 = 0.f, s1 = 0.f, s2 = 0.f, s3 = 0.f;
  int p = p0;
  for (; p + 4 <= p1; p += 4) {
    unsigned r0 = (unsigned)perm[p],     r1 = (unsigned)perm[p + 1];
    unsigned r2 = (unsigned)perm[p + 2], r3 = (unsigned)perm[p + 3];
    float e0 = e[r0], e1 = e[r1], e2 = e[r2], e3 = e[r3];
    float w0 = Wh[(size_t)r0 * OUT_CH + lane];
    float w1 = Wh[(size_t)r1 * OUT_CH + lane];
    float w2 = Wh[(size_t)r2 * OUT_CH + lane];
    float w3 = Wh[(size_t)r3 * OUT_CH + lane];
    float v0 = __expf(e0 + ec), v1 = __expf(e1 + ec);
    float v2 = __expf(e2 + ec), v3 = __expf(e3 + ec);
    a0 = fmaf(v0, w0, a0); s0 += v0;
    a1 = fmaf(v1, w1, a1); s1 += v1;
    a2 = fmaf(v2, w2, a2); s2 += v2;
    a3 = fmaf(v3, w3, a3); s3 += v3;
  }
  for (; p < p1; ++p) {
    unsigned r = (unsigned)perm[p];
    float v = __expf(e[r] + ec);
    a0 = fmaf(v, Wh[(size_t)r * OUT_CH + lane], a0); s0 += v;
  }
  float acc = (a0 + a1) + (a2 + a3);
  float ssum = (s0 + s1) + (s2 + s3);
  float rden = (p1 > p0) ? 1.0f / ssum : 0.0f;  // empty segment -> elu(0)=0
  acc *= rden;
  out[(size_t)c * OUT_CH + lane] = acc > 0.f ? acc : expm1f(acc);
}

extern "C" void kernel_launch(void* const* d_in, const int* in_sizes, int n_in,
                              void* d_out, int out_size, void* d_ws, size_t ws_size,
                              hipStream_t stream)
{
  const float* x     = (const float*)d_in[0];
  const void*  eidx  = d_in[1];
  const float* W     = (const float*)d_in[2];
  const float* a_src = (const float*)d_in[3];
  const float* a_dst = (const float*)d_in[4];
  float* out = (float*)d_out;

  const int n = in_sizes[0] / IN_CH;   // 50000
  const int E = in_sizes[1] / 2;       // 800000
  const int nb = (n + SCHUNK - 1) / SCHUNK;

  char* ws = (char*)d_ws;
  size_t off = 0;
  auto alloc = [&](size_t bytes) -> void* {
    void* p = ws + off;
    off = (off + bytes + 255) & ~(size_t)255;
    return p;
  };
  float*    Wh     = (float*)alloc((size_t)n * OUT_CH * 4);
  float*    e      = (float*)alloc((size_t)n * 4);
  void*     perm   = alloc((size_t)E * 4);   // ushort or uint, by n
  void*     rcbuf  = alloc((size_t)E * 8);   // packed u32 or uint2, by n
  void*     rank   = alloc((size_t)E * 4);   // u16 or u32, by n
  int*      cnt    = (int*)alloc((size_t)n * 4);
  int*      segp   = (int*)alloc((size_t)(n + 1) * 4);
  int*      bsum   = (int*)alloc((size_t)nb * 4);
  ushort*   Whi    = (ushort*)alloc((size_t)IN_CH * OUT_CH * 2);
  ushort*   Wlo    = (ushort*)alloc((size_t)IN_CH * OUT_CH * 2);
  unsigned* gmax   = (unsigned*)alloc(4);
  unsigned* flag   = (unsigned*)alloc(4);

  hipMemsetAsync(cnt,  0, (size_t)n * 4, stream);
  hipMemsetAsync(gmax, 0, 4, stream);
  hipMemsetAsync(flag, 0, 4, stream);

  gat_wprep<<<(IN_CH * OUT_CH + 255) / 256, 256, 0, stream>>>(W, Whi, Wlo);
  gat_gemm_mfma<<<(n + 31) / 32, 256, 0, stream>>>(x, Whi, Wlo, a_src, a_dst, Wh, e, gmax, n);

  gat_detect64<<<1, 256, 0, stream>>>((const unsigned*)eidx, flag, 8192);
  if (n <= 65536) {
    gat_pass1<ushort><<<(E + 255) / 256, 256, 0, stream>>>(
        eidx, flag, cnt, rcbuf, (ushort*)rank, E);
  } else {
    gat_pass1<unsigned><<<(E + 255) / 256, 256, 0, stream>>>(
        eidx, flag, cnt, rcbuf, (unsigned*)rank, E);
  }
  scan_partial<<<nb, 256, 0, stream>>>(cnt, bsum, n);
  scan_bsum<<<1, 256, 0, stream>>>(bsum, segp, nb, n, E);
  scan_final<<<nb, 256, 0, stream>>>(cnt, bsum, segp, n);
  if (n <= 65536) {
    gat_scatter<ushort><<<(E + 255) / 256, 256, 0, stream>>>(
        rcbuf, (const ushort*)rank, segp, (ushort*)perm, E);
    gat_aggregate<ushort><<<(n + 3) / 4, 256, 0, stream>>>(
        Wh, e, gmax, (const ushort*)perm, segp, out, n);
  } else {
    gat_scatter<unsigned><<<(E + 255) / 256, 256, 0, stream>>>(
        rcbuf, (const unsigned*)rank, segp, (unsigned*)perm, E);
    gat_aggregate<unsigned><<<(n + 3) / 4, 256, 0, stream>>>(
        Wh, e, gmax, (const unsigned*)perm, segp, out, n);
  }
}